// Round 9
// baseline (389.568 us; speedup 1.0000x reference)
//
#include <hip/hip_runtime.h>
#include <hip/hip_bf16.h>
#include <stdint.h>

#define T_TOK 4096
#define H_DIM 2048
#define I_DIM 1024
#define E_NUM 8
#define NPAIR 8192            // T_TOK * K_SEL
#define BM 128
#define MAX_TILES 72          // worst case sum(ceil(cnt_e/128)) = 64 + 7
#define CAP (MAX_TILES * BM)  // 9216 padded pair slots
#define NTB2 (MAX_TILES * 8)  // gemm grid = 576 (8 nt of 256 cols)

// prep_all grid layout
#define CVT_BLKS 1024
#define GU_BLKS 4096          // 8192 gu 64x64 tiles, 2 per block
#define D_BLKS 2048           // 4096 d 64x64 tiles, 2 per block
#define PREP_BLKS (CVT_BLKS + GU_BLKS + D_BLKS + 1)

typedef short s16x8 __attribute__((ext_vector_type(8)));
typedef __bf16 bf16x8 __attribute__((ext_vector_type(8)));
typedef float f32x4 __attribute__((ext_vector_type(4)));

using gas1_t = const __attribute__((address_space(1))) void*;
using las3_t = __attribute__((address_space(3))) void*;

__device__ __forceinline__ void async_lds16(const void* g, void* l) {
  __builtin_amdgcn_global_load_lds((gas1_t)(uintptr_t)g,
                                   (las3_t)(uint32_t)(uintptr_t)l, 16, 0, 0);
}

__device__ __forceinline__ unsigned short f2bf(float f) {
  union { float f; unsigned int u; } v; v.f = f;
  unsigned int r = v.u + 0x7FFF + ((v.u >> 16) & 1); // RNE
  return (unsigned short)(r >> 16);
}

__device__ __forceinline__ f32x4 mfma_bf16(s16x8 a, s16x8 b, f32x4 c) {
  return __builtin_amdgcn_mfma_f32_16x16x32_bf16(
      __builtin_bit_cast(bf16x8, a), __builtin_bit_cast(bf16x8, b), c, 0, 0, 0);
}

__device__ __forceinline__ unsigned short gelu_mul_bf16(float g, float u) {
  const float z = 0.7978845608028654f * (g + 0.044715f * g * g * g);
  const float ex = __expf(2.f * z);
  const float th = (ex - 1.f) / (ex + 1.f);
  return f2bf(0.5f * g * (1.f + th) * u);
}

__device__ __forceinline__ float bflo(unsigned int u) {
  return __uint_as_float(u << 16);
}
__device__ __forceinline__ float bfhi(unsigned int u) {
  return __uint_as_float(u & 0xFFFF0000u);
}

// ===== prep: cvt x + transpose(Wg,Wu->WguT) + transpose(Wd->WdT) + routing ==
// (identical to round-5..8 passing version; LDS stride 73 = conflict-free)
__global__ __launch_bounds__(512)
void prep_all(const float4* __restrict__ x4, ushort4* __restrict__ xb4,
              const float* __restrict__ Wg, const float* __restrict__ Wu,
              const float* __restrict__ Wd,
              unsigned short* __restrict__ WguT,
              unsigned short* __restrict__ WdT,
              const int* __restrict__ sel, const float* __restrict__ rw,
              int* __restrict__ pair_token, float* __restrict__ pair_weight,
              int* __restrict__ inv,
              int* __restrict__ tile_expert, int* __restrict__ tile_pos) {
  const int bid = blockIdx.x;
  const int tid = threadIdx.x;

  if (bid < CVT_BLKS) {                    // ---- cvt x -> bf16 ----
    int i = bid * 512 + tid;
    const int stride = CVT_BLKS * 512;
#pragma unroll
    for (int q = 0; q < 4; ++q) {
      const float4 v = x4[i];
      ushort4 r;
      r.x = f2bf(v.x); r.y = f2bf(v.y); r.z = f2bf(v.z); r.w = f2bf(v.w);
      xb4[i] = r;
      i += stride;
    }
    return;
  }

  if (bid < CVT_BLKS + GU_BLKS + D_BLKS) { // ---- weight transposes ----
    __shared__ unsigned short Tl[2][64 * 73];
    const int sub = tid >> 8, k = tid & 255;
    const int rr = k >> 2, cb = (k & 3) * 16;
    const int oc = k >> 2, rb = (k & 3) * 16;

    if (bid < CVT_BLKS + GU_BLKS) {        // Wg/Wu -> WguT (g/u interleaved)
      const int t3 = (bid - CVT_BLKS) * 2 + sub;    // [0, 8192)
      const int which = t3 >> 12;                   // 0=gate, 1=up
      const int e = (t3 >> 9) & 7;
      const int tile = t3 & 511;                    // 32 h-tiles x 16 i-tiles
      const int r0 = (tile >> 4) * 64;              // h base
      const int c0 = (tile & 15) * 64;              // i base
      const float* src = (which ? Wu : Wg) + (size_t)e * H_DIM * I_DIM;
      const float4* s4 = (const float4*)(src + (size_t)(r0 + rr) * I_DIM + c0 + cb);
      unsigned short* dl = &Tl[sub][rr * 73 + cb];
#pragma unroll
      for (int q = 0; q < 4; ++q) {
        const float4 v = s4[q];
        dl[q * 4 + 0] = f2bf(v.x); dl[q * 4 + 1] = f2bf(v.y);
        dl[q * 4 + 2] = f2bf(v.z); dl[q * 4 + 3] = f2bf(v.w);
      }
      __syncthreads();
      union { unsigned short us[16]; uint4 u4[2]; } pk;
#pragma unroll
      for (int m = 0; m < 16; ++m) pk.us[m] = Tl[sub][(rb + m) * 73 + oc];
      const int gi = c0 + oc;
      const int orow = (gi >> 4) * 32 + (gi & 15) + which * 16;
      uint4* d4 = (uint4*)(WguT + ((size_t)e * 2048 + orow) * H_DIM + r0 + rb);
      d4[0] = pk.u4[0]; d4[1] = pk.u4[1];
    } else {                               // Wd -> WdT (i'-permuted cols)
      const int t3 = (bid - CVT_BLKS - GU_BLKS) * 2 + sub;  // [0, 4096)
      const int e = t3 >> 9;
      const int tile = t3 & 511;                    // 16 i-tiles x 32 h-tiles
      const int r0 = (tile >> 5) * 64;              // i base
      const int c0 = (tile & 31) * 64;              // h base
      const float* src = Wd + (size_t)e * I_DIM * H_DIM;
      const float4* s4 = (const float4*)(src + (size_t)(r0 + rr) * H_DIM + c0 + cb);
      unsigned short* dl = &Tl[sub][rr * 73 + cb];
#pragma unroll
      for (int q = 0; q < 4; ++q) {
        const float4 v = s4[q];
        dl[q * 4 + 0] = f2bf(v.x); dl[q * 4 + 1] = f2bf(v.y);
        dl[q * 4 + 2] = f2bf(v.z); dl[q * 4 + 3] = f2bf(v.w);
      }
      __syncthreads();
      union { unsigned short us[16]; uint4 u4[2]; } pk;
#pragma unroll
      for (int m = 0; m < 16; ++m) {
        const int il = rb + m;                      // i' local [0,64)
        const int isrc = (il & 32) + ((il & 1) << 4) + ((il >> 1) & 15);
        pk.us[m] = Tl[sub][isrc * 73 + oc];
      }
      const int gh = c0 + oc;
      uint4* d4 = (uint4*)(WdT + ((size_t)e * H_DIM + gh) * I_DIM + r0 + rb);
      d4[0] = pk.u4[0]; d4[1] = pk.u4[1];
    }
    return;
  }

  // ---- routing (single block) ----
  __shared__ int cnt[E_NUM], off[E_NUM], fil[E_NUM];
  if (tid < E_NUM) { cnt[tid] = 0; fil[tid] = 0; }
  __syncthreads();
  for (int p = tid; p < NPAIR; p += 512) atomicAdd(&cnt[sel[p]], 1);
  for (int q = tid; q < CAP; q += 512) { pair_token[q] = 0; pair_weight[q] = 0.f; }
  __syncthreads();
  if (tid == 0) {
    int run = 0, idx = 0;
    for (int e = 0; e < E_NUM; ++e) {
      off[e] = run;
      const int nt = (cnt[e] + BM - 1) / BM;
      for (int t = 0; t < nt; ++t) { tile_expert[idx] = e; tile_pos[idx] = run + t * BM; ++idx; }
      run += nt * BM;
    }
    for (; idx < MAX_TILES; ++idx) tile_expert[idx] = -1;
  }
  __syncthreads();
  for (int p = tid; p < NPAIR; p += 512) {
    const int e = sel[p];
    const int pos = off[e] + atomicAdd(&fil[e], 1);
    pair_token[pos] = p >> 1;   // K_SEL == 2
    pair_weight[pos] = rw[p];
    inv[p] = pos;
  }
}

// ====== 128x256 8-wave GEMM: A via LDS DMA (3-slot), B DIRECT to registers ==
// MODE 0: A = xb gathered by pair_token (K=2048), B = WguT -> a_pair packed u32
// MODE 1: A = a_pair (K=1024, i' order), B = WdT -> d_pair bf16 (w applied)
// B fragment = global_load_dwordx4: lanes {fr+16*fq} read row fr at 4 adjacent
// 16B chunks -> 16 rows x 64B coalesced from L2. bCur/bNext named double
// buffer (no dynamic indexing). One barrier per K-step; fused
// s_waitcnt vmcnt(K) lgkmcnt(0): K=10 steady (A(t+1) slot + B(t) regs done),
// 8 at NT-2, 0 at NT-1. A staging = 16KB/K-step only (vs 48KB in r4-r8).
template<int MODE>
__global__ __launch_bounds__(512, 2)
void moe_gemm(const unsigned short* __restrict__ Aop,
              const unsigned short* __restrict__ Bop,
              const int* __restrict__ pair_token,
              const float* __restrict__ pair_weight,
              const int* __restrict__ tile_expert,
              const int* __restrict__ tile_pos,
              unsigned int* __restrict__ a32,
              unsigned short* __restrict__ d_pair) {
  constexpr int KD = (MODE == 0) ? H_DIM : I_DIM;
  constexpr int NT = KD / 64;

  extern __shared__ unsigned short sA[];   // 3 slots x 8192 shorts (48 KB)

  const int bid = blockIdx.x;
  const int mt = bid >> 3;               // mt sweeps within each XCD
  const int nt = bid & 7;                // nt == XCD id (round-robin dispatch)
  const int e = tile_expert[mt];
  if (e < 0) return;
  const int pbase = tile_pos[mt];

  const int tid = threadIdx.x;
  const int wv = tid >> 6;               // 0..7
  const int lane = tid & 63;
  const int fr = lane & 15;
  const int fq = lane >> 4;
  const int wm = (wv >> 2) * 64;         // 0/64
  const int wn = (wv & 3) * 64;          // 0/64/128/192

  // ---- A staging sources (pre-swizzled 16B chunks), 2 loads/wave/K-step
  const int rloc = lane >> 3;            // 0..7
  const int gch = (lane & 7) ^ rloc;     // row&7 == rloc for every op
  const unsigned short* pa[2];
#pragma unroll
  for (int j = 0; j < 2; ++j) {
    const int row = j * 64 + wv * 8 + rloc;   // 0..127
    size_t arow;
    if constexpr (MODE == 0) arow = (size_t)pair_token[pbase + row];
    else                     arow = (size_t)(pbase + row);
    pa[j] = Aop + arow * KD + gch * 8;
  }

  // ---- A LDS fragment offsets (shorts); row stride 64, XOR chunk swizzle
  int aoff[4][2];
#pragma unroll
  for (int f = 0; f < 4; ++f)
#pragma unroll
    for (int kk = 0; kk < 2; ++kk) {
      const int ra = wm + f * 16 + fr;
      aoff[f][kk] = ra * 64 + (((kk * 4 + fq) ^ (ra & 7)) * 8);
    }

  // ---- B direct-load fragment pointers: row (nt*256+wn+nf*16+fr), chunk fq
  const unsigned short* Be = Bop + (size_t)e * 2048 * KD;
  const unsigned short* pB[4][2];
#pragma unroll
  for (int nf = 0; nf < 4; ++nf)
#pragma unroll
    for (int kk = 0; kk < 2; ++kk) {
      const int rb = nt * 256 + wn + nf * 16 + fr;
      pB[nf][kk] = Be + (size_t)rb * KD + (kk * 4 + fq) * 8;
    }

  f32x4 acc[4][4] = {};
  s16x8 aF[4][2];
  s16x8 bufA[4][2], bufB[4][2];

#define STAGE_A(T, S)                                                        \
  {                                                                          \
    unsigned short* _d = sA + (S) * 8192 + wv * 512;                         \
    _Pragma("unroll")                                                        \
    for (int j = 0; j < 2; ++j)                                              \
      async_lds16(pa[j] + (size_t)(T) * 64, _d + j * 4096);                  \
  }

  // ---- prologue: A slots 0,1 in flight; B(0) -> bufA
  STAGE_A(0, 0);
  STAGE_A(1, 1);
#pragma unroll
  for (int nf = 0; nf < 4; ++nf)
#pragma unroll
    for (int kk = 0; kk < 2; ++kk)
      bufA[nf][kk] = *(const s16x8*)(pB[nf][kk]);
  asm volatile("s_waitcnt vmcnt(10)" ::: "memory");   // A(0) resident
  __builtin_amdgcn_s_barrier();
  __builtin_amdgcn_sched_barrier(0);

  int sCur = 0, sNxt2 = 2;

#define KSTEP(T, BCUR, BNXT)                                                 \
  {                                                                          \
    const int _t = (T);                                                      \
    const unsigned short* As = sA + sCur * 8192;                             \
    _Pragma("unroll")                                                        \
    for (int mf = 0; mf < 4; ++mf)                                           \
      _Pragma("unroll")                                                      \
      for (int kk = 0; kk < 2; ++kk)                                         \
        aF[mf][kk] = *(const s16x8*)&As[aoff[mf][kk]];                       \
    if (_t + 2 < NT) STAGE_A(_t + 2, sNxt2);                                 \
    if (_t + 1 < NT) {                                                       \
      _Pragma("unroll")                                                      \
      for (int nf = 0; nf < 4; ++nf)                                         \
        _Pragma("unroll")                                                    \
        for (int kk = 0; kk < 2; ++kk)                                       \
          BNXT[nf][kk] = *(const s16x8*)(pB[nf][kk] + (size_t)(_t + 1) * 64);\
    }                                                                        \
    if (_t < NT - 2)                                                         \
      asm volatile("s_waitcnt vmcnt(10) lgkmcnt(0)" ::: "memory");           \
    else if (_t == NT - 2)                                                   \
      asm volatile("s_waitcnt vmcnt(8) lgkmcnt(0)" ::: "memory");            \
    else                                                                     \
      asm volatile("s_waitcnt vmcnt(0) lgkmcnt(0)" ::: "memory");            \
    __builtin_amdgcn_s_barrier();                                            \
    __builtin_amdgcn_sched_barrier(0);                                       \
    __builtin_amdgcn_s_setprio(1);                                           \
    _Pragma("unroll")                                                        \
    for (int kk = 0; kk < 2; ++kk)                                           \
      _Pragma("unroll")                                                      \
      for (int mf = 0; mf < 4; ++mf)                                         \
        _Pragma("unroll")                                                    \
        for (int nf = 0; nf < 4; ++nf)                                       \
          acc[mf][nf] = mfma_bf16(aF[mf][kk], BCUR[nf][kk], acc[mf][nf]);    \
    __builtin_amdgcn_s_setprio(0);                                           \
    sCur = (sCur == 2) ? 0 : sCur + 1;                                       \
    sNxt2 = (sNxt2 == 2) ? 0 : sNxt2 + 1;                                    \
  }

  for (int t = 0; t < NT; t += 2) {
    KSTEP(t, bufA, bufB);
    KSTEP(t + 1, bufB, bufA);
  }
#undef KSTEP
#undef STAGE_A

  if constexpr (MODE == 0) {
    // packed epilogue: (nf0,nf1)=(g,u) of i, (nf2,nf3)=(g,u) of i+16
    const int cidx = (nt * 4 + (wn >> 6)) * 16 + fr;   // dword index in row
#pragma unroll
    for (int mf = 0; mf < 4; ++mf)
#pragma unroll
      for (int jj = 0; jj < 4; ++jj) {
        const int row = pbase + wm + mf * 16 + fq * 4 + jj;
        const unsigned int h0 = gelu_mul_bf16(acc[mf][0][jj], acc[mf][1][jj]);
        const unsigned int h1 = gelu_mul_bf16(acc[mf][2][jj], acc[mf][3][jj]);
        a32[(size_t)row * (I_DIM / 2) + cidx] = h0 | (h1 << 16);
      }
  } else {
    // plain bf16 stores of w*d into d_pair (combine sums the two experts)
#pragma unroll
    for (int mf = 0; mf < 4; ++mf)
#pragma unroll
      for (int jj = 0; jj < 4; ++jj) {
        const int prow = pbase + wm + mf * 16 + fq * 4 + jj;
        const float w = pair_weight[prow];
        unsigned short* dp = d_pair + (size_t)prow * H_DIM + nt * 256 + wn + fr;
#pragma unroll
        for (int nf = 0; nf < 4; ++nf)
          dp[nf * 16] = f2bf(w * acc[mf][nf][jj]);
      }
  }
}

// ========================= combine: out[t] = d[p0] + d[p1] =================
__global__ __launch_bounds__(256)
void combine(const unsigned short* __restrict__ d_pair,
             const int* __restrict__ inv,
             float* __restrict__ out) {
  const int tid = threadIdx.x;
  const int tok = blockIdx.x * 2 + (tid >> 7);
  const int ln = tid & 127;
  const int p0 = inv[2 * tok], p1 = inv[2 * tok + 1];
  const uint4* r0 = (const uint4*)(d_pair + (size_t)p0 * H_DIM);
  const uint4* r1 = (const uint4*)(d_pair + (size_t)p1 * H_DIM);
  float4* o = (float4*)(out + (size_t)tok * H_DIM);
#pragma unroll
  for (int j = 0; j < 2; ++j) {
    const int c = ln + j * 128;               // uint4 index, 256 per row
    const uint4 a = r0[c];
    const uint4 b = r1[c];
    float4 fa, fb;
    fa.x = bflo(a.x) + bflo(b.x); fa.y = bfhi(a.x) + bfhi(b.x);
    fa.z = bflo(a.y) + bflo(b.y); fa.w = bfhi(a.y) + bfhi(b.y);
    fb.x = bflo(a.z) + bflo(b.z); fb.y = bfhi(a.z) + bfhi(b.z);
    fb.z = bflo(a.w) + bflo(b.w); fb.w = bfhi(a.w) + bfhi(b.w);
    o[2 * c] = fa;
    o[2 * c + 1] = fb;
  }
}

// ================================= launch ==================================
extern "C" void kernel_launch(void* const* d_in, const int* in_sizes, int n_in,
                              void* d_out, int out_size, void* d_ws, size_t ws_size,
                              hipStream_t stream) {
  const float* x  = (const float*)d_in[0];
  const float* Wg = (const float*)d_in[1];
  const float* Wu = (const float*)d_in[2];
  const float* Wd = (const float*)d_in[3];
  const int*   sel = (const int*)d_in[4];
  const float* rw  = (const float*)d_in[5];
  float* out = (float*)d_out;

  char* base = (char*)d_ws;
  size_t off = 0;
  auto take = [&](size_t bytes) { char* p = base + off; off += bytes; return p; };
  unsigned short* xb     = (unsigned short*)take((size_t)T_TOK * H_DIM * 2);
  unsigned short* WguT   = (unsigned short*)take((size_t)E_NUM * 2048 * H_DIM * 2);
  unsigned short* WdT    = (unsigned short*)take((size_t)E_NUM * H_DIM * I_DIM * 2);
  unsigned short* a_pair = (unsigned short*)take((size_t)CAP * I_DIM * 2);
  unsigned short* d_pair = (unsigned short*)take((size_t)CAP * H_DIM * 2);
  int*   pair_token  = (int*)take(CAP * 4);
  float* pair_weight = (float*)take(CAP * 4);
  int*   inv         = (int*)take(NPAIR * 4);
  int*   tile_expert = (int*)take(512);
  int*   tile_pos    = (int*)take(512);
  (void)off;

  hipFuncSetAttribute((const void*)&moe_gemm<0>,
                      hipFuncAttributeMaxDynamicSharedMemorySize, 49152);
  hipFuncSetAttribute((const void*)&moe_gemm<1>,
                      hipFuncAttributeMaxDynamicSharedMemorySize, 49152);

  prep_all<<<PREP_BLKS, 512, 0, stream>>>(
      (const float4*)x, (ushort4*)xb, Wg, Wu, Wd, WguT, WdT, sel, rw,
      pair_token, pair_weight, inv, tile_expert, tile_pos);

  moe_gemm<0><<<NTB2, 512, 49152, stream>>>(
      xb, WguT, pair_token, pair_weight, tile_expert, tile_pos,
      (unsigned int*)a_pair, nullptr);

  moe_gemm<1><<<NTB2, 512, 49152, stream>>>(
      a_pair, WdT, pair_token, pair_weight, tile_expert, tile_pos,
      nullptr, d_pair);

  combine<<<T_TOK / 2, 256, 0, stream>>>(d_pair, inv, out);
}

// Round 10
// 261.911 us; speedup vs baseline: 1.4874x; 1.4874x over previous
//
#include <hip/hip_runtime.h>
#include <hip/hip_bf16.h>
#include <stdint.h>

#define T_TOK 4096
#define H_DIM 2048
#define I_DIM 1024
#define E_NUM 8
#define NPAIR 8192            // T_TOK * K_SEL
#define BM 256
#define MAX_TILES 40          // worst case sum(ceil(cnt_e/256)) = 32 + 7
#define CAP (MAX_TILES * BM)  // 10240 padded pair slots
#define NTB (MAX_TILES * 8)   // gemm grid = 320 (8 nt bands of 256 cols)

// prep_all grid layout
#define CVT_BLKS 1024
#define GU_BLKS 4096          // 8192 gu 64x64 tiles, 2 per block
#define D_BLKS 2048           // 4096 d 64x64 tiles, 2 per block
#define PREP_BLKS (CVT_BLKS + GU_BLKS + D_BLKS + 1)

typedef short s16x8 __attribute__((ext_vector_type(8)));
typedef __bf16 bf16x8 __attribute__((ext_vector_type(8)));
typedef float f32x4 __attribute__((ext_vector_type(4)));

using gas1_t = const __attribute__((address_space(1))) void*;
using las3_t = __attribute__((address_space(3))) void*;

__device__ __forceinline__ void async_lds16(const void* g, void* l) {
  __builtin_amdgcn_global_load_lds((gas1_t)(uintptr_t)g,
                                   (las3_t)(uint32_t)(uintptr_t)l, 16, 0, 0);
}

__device__ __forceinline__ unsigned short f2bf(float f) {
  union { float f; unsigned int u; } v; v.f = f;
  unsigned int r = v.u + 0x7FFF + ((v.u >> 16) & 1); // RNE
  return (unsigned short)(r >> 16);
}

__device__ __forceinline__ f32x4 mfma_bf16(s16x8 a, s16x8 b, f32x4 c) {
  return __builtin_amdgcn_mfma_f32_16x16x32_bf16(
      __builtin_bit_cast(bf16x8, a), __builtin_bit_cast(bf16x8, b), c, 0, 0, 0);
}

__device__ __forceinline__ unsigned short gelu_mul_bf16(float g, float u) {
  const float z = 0.7978845608028654f * (g + 0.044715f * g * g * g);
  const float ex = __expf(2.f * z);
  const float th = (ex - 1.f) / (ex + 1.f);
  return f2bf(0.5f * g * (1.f + th) * u);
}

__device__ __forceinline__ float bflo(unsigned int u) {
  return __uint_as_float(u << 16);
}
__device__ __forceinline__ float bfhi(unsigned int u) {
  return __uint_as_float(u & 0xFFFF0000u);
}

// ===== prep: cvt x + transpose(Wg,Wu->WguT) + transpose(Wd->WdT) + routing ==
// (identical to round-5..8 passing version; LDS stride 73 = conflict-free)
__global__ __launch_bounds__(512)
void prep_all(const float4* __restrict__ x4, ushort4* __restrict__ xb4,
              const float* __restrict__ Wg, const float* __restrict__ Wu,
              const float* __restrict__ Wd,
              unsigned short* __restrict__ WguT,
              unsigned short* __restrict__ WdT,
              const int* __restrict__ sel, const float* __restrict__ rw,
              int* __restrict__ pair_token, float* __restrict__ pair_weight,
              int* __restrict__ inv,
              int* __restrict__ tile_expert, int* __restrict__ tile_pos) {
  const int bid = blockIdx.x;
  const int tid = threadIdx.x;

  if (bid < CVT_BLKS) {                    // ---- cvt x -> bf16 ----
    int i = bid * 512 + tid;
    const int stride = CVT_BLKS * 512;
#pragma unroll
    for (int q = 0; q < 4; ++q) {
      const float4 v = x4[i];
      ushort4 r;
      r.x = f2bf(v.x); r.y = f2bf(v.y); r.z = f2bf(v.z); r.w = f2bf(v.w);
      xb4[i] = r;
      i += stride;
    }
    return;
  }

  if (bid < CVT_BLKS + GU_BLKS + D_BLKS) { // ---- weight transposes ----
    __shared__ unsigned short Tl[2][64 * 73];
    const int sub = tid >> 8, k = tid & 255;
    const int rr = k >> 2, cb = (k & 3) * 16;
    const int oc = k >> 2, rb = (k & 3) * 16;

    if (bid < CVT_BLKS + GU_BLKS) {        // Wg/Wu -> WguT (g/u interleaved)
      const int t3 = (bid - CVT_BLKS) * 2 + sub;    // [0, 8192)
      const int which = t3 >> 12;                   // 0=gate, 1=up
      const int e = (t3 >> 9) & 7;
      const int tile = t3 & 511;                    // 32 h-tiles x 16 i-tiles
      const int r0 = (tile >> 4) * 64;              // h base
      const int c0 = (tile & 15) * 64;              // i base
      const float* src = (which ? Wu : Wg) + (size_t)e * H_DIM * I_DIM;
      const float4* s4 = (const float4*)(src + (size_t)(r0 + rr) * I_DIM + c0 + cb);
      unsigned short* dl = &Tl[sub][rr * 73 + cb];
#pragma unroll
      for (int q = 0; q < 4; ++q) {
        const float4 v = s4[q];
        dl[q * 4 + 0] = f2bf(v.x); dl[q * 4 + 1] = f2bf(v.y);
        dl[q * 4 + 2] = f2bf(v.z); dl[q * 4 + 3] = f2bf(v.w);
      }
      __syncthreads();
      union { unsigned short us[16]; uint4 u4[2]; } pk;
#pragma unroll
      for (int m = 0; m < 16; ++m) pk.us[m] = Tl[sub][(rb + m) * 73 + oc];
      const int gi = c0 + oc;
      const int orow = (gi >> 4) * 32 + (gi & 15) + which * 16;
      uint4* d4 = (uint4*)(WguT + ((size_t)e * 2048 + orow) * H_DIM + r0 + rb);
      d4[0] = pk.u4[0]; d4[1] = pk.u4[1];
    } else {                               // Wd -> WdT (i'-permuted cols)
      const int t3 = (bid - CVT_BLKS - GU_BLKS) * 2 + sub;  // [0, 4096)
      const int e = t3 >> 9;
      const int tile = t3 & 511;                    // 16 i-tiles x 32 h-tiles
      const int r0 = (tile >> 5) * 64;              // i base
      const int c0 = (tile & 31) * 64;              // h base
      const float* src = Wd + (size_t)e * I_DIM * H_DIM;
      const float4* s4 = (const float4*)(src + (size_t)(r0 + rr) * H_DIM + c0 + cb);
      unsigned short* dl = &Tl[sub][rr * 73 + cb];
#pragma unroll
      for (int q = 0; q < 4; ++q) {
        const float4 v = s4[q];
        dl[q * 4 + 0] = f2bf(v.x); dl[q * 4 + 1] = f2bf(v.y);
        dl[q * 4 + 2] = f2bf(v.z); dl[q * 4 + 3] = f2bf(v.w);
      }
      __syncthreads();
      union { unsigned short us[16]; uint4 u4[2]; } pk;
#pragma unroll
      for (int m = 0; m < 16; ++m) {
        const int il = rb + m;                      // i' local [0,64)
        const int isrc = (il & 32) + ((il & 1) << 4) + ((il >> 1) & 15);
        pk.us[m] = Tl[sub][isrc * 73 + oc];
      }
      const int gh = c0 + oc;
      uint4* d4 = (uint4*)(WdT + ((size_t)e * H_DIM + gh) * I_DIM + r0 + rb);
      d4[0] = pk.u4[0]; d4[1] = pk.u4[1];
    }
    return;
  }

  // ---- routing (single block), BM=256 tiles ----
  __shared__ int cnt[E_NUM], off[E_NUM], fil[E_NUM];
  if (tid < E_NUM) { cnt[tid] = 0; fil[tid] = 0; }
  __syncthreads();
  for (int p = tid; p < NPAIR; p += 512) atomicAdd(&cnt[sel[p]], 1);
  for (int q = tid; q < CAP; q += 512) { pair_token[q] = 0; pair_weight[q] = 0.f; }
  __syncthreads();
  if (tid == 0) {
    int run = 0, idx = 0;
    for (int e = 0; e < E_NUM; ++e) {
      off[e] = run;
      const int nt = (cnt[e] + BM - 1) / BM;
      for (int t = 0; t < nt; ++t) { tile_expert[idx] = e; tile_pos[idx] = run + t * BM; ++idx; }
      run += nt * BM;
    }
    for (; idx < MAX_TILES; ++idx) tile_expert[idx] = -1;
  }
  __syncthreads();
  for (int p = tid; p < NPAIR; p += 512) {
    const int e = sel[p];
    const int pos = off[e] + atomicAdd(&fil[e], 1);
    pair_token[pos] = p >> 1;   // K_SEL == 2
    pair_weight[pos] = rw[p];
    inv[p] = pos;
  }
}

// ====== 256x256 8-wave GEMM, BK=32, 4-slot ring, stage t+3, vmcnt(8) =======
// MODE 0: A = xb gathered by pair_token (K=2048), B = WguT -> a_pair packed u32
// MODE 1: A = a_pair (K=1024, i' order), B = WdT -> d_pair bf16 (w applied)
// Tile needs 26 B/cyc staging per MFMA-cycle (vs 39.6 at 128x256) and stages
// ~610MB total (vs 864MB). Wave tile 128x64 (2M x 4N). LDS: 2 ops x 4 slots x
// 16KB = 128KB. Ledger (4 loads/wave/step): steady vmcnt(8) retires tile t+1
// (issued 2 steps earlier); tail vmcnt(4) -> vmcnt(0). BK=32 chunk swizzle
// fq^((fr>>1)&3): 2-way bank alias only (free, m136).
template<int MODE>
__global__ __launch_bounds__(512, 1)
void moe_gemm(const unsigned short* __restrict__ Aop,
              const unsigned short* __restrict__ Bop,
              const int* __restrict__ pair_token,
              const float* __restrict__ pair_weight,
              const int* __restrict__ tile_expert,
              const int* __restrict__ tile_pos,
              unsigned int* __restrict__ a32,
              unsigned short* __restrict__ d_pair) {
  constexpr int KD = (MODE == 0) ? H_DIM : I_DIM;
  constexpr int NT = KD / 32;

  extern __shared__ unsigned short smem[];
  unsigned short* sA = smem;             // 4 slots x 8192 shorts (16KB)
  unsigned short* sB = smem + 4 * 8192;  // 4 slots x 8192 shorts

  const int bid = blockIdx.x;
  const int mt = bid >> 3;               // mt sweeps within each XCD
  const int nt = bid & 7;                // nt == XCD id (round-robin dispatch)
  const int e = tile_expert[mt];
  if (e < 0) return;
  const int pbase = tile_pos[mt];

  const int tid = threadIdx.x;
  const int wv = tid >> 6;               // 0..7
  const int lane = tid & 63;
  const int fr = lane & 15;
  const int fq = lane >> 4;
  const int wm = (wv >> 2) * 128;        // 0/128
  const int wn = (wv & 3) * 64;          // 0/64/128/192

  // ---- staging sources: per wave 2 gloads per operand per K-step
  // gload j covers rows j*128 + wv*16 + (lane>>2), 4 lanes x 16B per row
  const int rr = lane >> 2;              // 0..15
  const int gch = (lane & 3) ^ ((lane >> 3) & 3);   // pre-swizzled chunk
  const unsigned short* pa[2];
  const unsigned short* pb[2];
  const unsigned short* Be = Bop + (size_t)e * 2048 * KD;
#pragma unroll
  for (int j = 0; j < 2; ++j) {
    const int row = j * 128 + wv * 16 + rr;   // 0..255
    size_t arow;
    if constexpr (MODE == 0) arow = (size_t)pair_token[pbase + row];
    else                     arow = (size_t)(pbase + row);
    pa[j] = Aop + arow * KD + gch * 8;
    pb[j] = Be + (size_t)(nt * 256 + row) * KD + gch * 8;
  }

  // ---- LDS read offsets (shorts); row = 32 shorts, chunk swizzle fq^((fr>>1)&3)
  const int csw = (fq ^ ((fr >> 1) & 3)) * 8;
  int aoff[8], boff[4];
#pragma unroll
  for (int mf = 0; mf < 8; ++mf) aoff[mf] = (wm + mf * 16 + fr) * 32 + csw;
#pragma unroll
  for (int nf = 0; nf < 4; ++nf) boff[nf] = (wn + nf * 16 + fr) * 32 + csw;

  f32x4 acc[8][4] = {};

#define STAGE(T, S)                                                          \
  {                                                                          \
    unsigned short* _da = sA + (S) * 8192 + wv * 512;                        \
    unsigned short* _db = sB + (S) * 8192 + wv * 512;                        \
    _Pragma("unroll")                                                        \
    for (int j = 0; j < 2; ++j) {                                            \
      async_lds16(pa[j] + (size_t)(T) * 32, _da + j * 4096);                 \
      async_lds16(pb[j] + (size_t)(T) * 32, _db + j * 4096);                 \
    }                                                                        \
  }

  // prologue: tiles 0,1,2 in flight (12 loads/wave); tile 0 resident
  STAGE(0, 0); STAGE(1, 1); STAGE(2, 2);
  asm volatile("s_waitcnt vmcnt(8)" ::: "memory");
  __builtin_amdgcn_s_barrier();
  __builtin_amdgcn_sched_barrier(0);

  for (int t = 0; t < NT; ++t) {
    const unsigned short* As = sA + (t & 3) * 8192;
    const unsigned short* Bs = sB + (t & 3) * 8192;
    s16x8 aF[8], bF[4];
#pragma unroll
    for (int mf = 0; mf < 8; ++mf) aF[mf] = *(const s16x8*)&As[aoff[mf]];
#pragma unroll
    for (int nf = 0; nf < 4; ++nf) bF[nf] = *(const s16x8*)&Bs[boff[nf]];
    if (t + 3 < NT) {
      STAGE(t + 3, (t + 3) & 3);
      asm volatile("s_waitcnt vmcnt(8) lgkmcnt(0)" ::: "memory");
    } else if (t + 3 == NT) {
      asm volatile("s_waitcnt vmcnt(4) lgkmcnt(0)" ::: "memory");
    } else {
      asm volatile("s_waitcnt vmcnt(0) lgkmcnt(0)" ::: "memory");
    }
    __builtin_amdgcn_s_barrier();
    __builtin_amdgcn_sched_barrier(0);
    __builtin_amdgcn_s_setprio(1);
#pragma unroll
    for (int mf = 0; mf < 8; ++mf)
#pragma unroll
      for (int nf = 0; nf < 4; ++nf)
        acc[mf][nf] = mfma_bf16(aF[mf], bF[nf], acc[mf][nf]);
    __builtin_amdgcn_s_setprio(0);
  }
#undef STAGE

  if constexpr (MODE == 0) {
    // packed epilogue: (nf0,nf1)=(g,u) of i-block q, (nf2,nf3)=(g,u) of q+1
    const int cidx = (nt * 4 + (wn >> 6)) * 16 + fr;   // dword index in row
#pragma unroll
    for (int mf = 0; mf < 8; ++mf)
#pragma unroll
      for (int jj = 0; jj < 4; ++jj) {
        const int row = pbase + wm + mf * 16 + fq * 4 + jj;
        const unsigned int h0 = gelu_mul_bf16(acc[mf][0][jj], acc[mf][1][jj]);
        const unsigned int h1 = gelu_mul_bf16(acc[mf][2][jj], acc[mf][3][jj]);
        a32[(size_t)row * (I_DIM / 2) + cidx] = h0 | (h1 << 16);
      }
  } else {
    // plain bf16 stores of w*d into d_pair (combine sums the two experts)
#pragma unroll
    for (int mf = 0; mf < 8; ++mf)
#pragma unroll
      for (int jj = 0; jj < 4; ++jj) {
        const int prow = pbase + wm + mf * 16 + fq * 4 + jj;
        const float w = pair_weight[prow];
        unsigned short* dp = d_pair + (size_t)prow * H_DIM + nt * 256 + wn + fr;
#pragma unroll
        for (int nf = 0; nf < 4; ++nf)
          dp[nf * 16] = f2bf(w * acc[mf][nf][jj]);
      }
  }
}

// ========================= combine: out[t] = d[p0] + d[p1] =================
__global__ __launch_bounds__(256)
void combine(const unsigned short* __restrict__ d_pair,
             const int* __restrict__ inv,
             float* __restrict__ out) {
  const int tid = threadIdx.x;
  const int tok = blockIdx.x * 2 + (tid >> 7);
  const int ln = tid & 127;
  const int p0 = inv[2 * tok], p1 = inv[2 * tok + 1];
  const uint4* r0 = (const uint4*)(d_pair + (size_t)p0 * H_DIM);
  const uint4* r1 = (const uint4*)(d_pair + (size_t)p1 * H_DIM);
  float4* o = (float4*)(out + (size_t)tok * H_DIM);
#pragma unroll
  for (int j = 0; j < 2; ++j) {
    const int c = ln + j * 128;               // uint4 index, 256 per row
    const uint4 a = r0[c];
    const uint4 b = r1[c];
    float4 fa, fb;
    fa.x = bflo(a.x) + bflo(b.x); fa.y = bfhi(a.x) + bfhi(b.x);
    fa.z = bflo(a.y) + bflo(b.y); fa.w = bfhi(a.y) + bfhi(b.y);
    fb.x = bflo(a.z) + bflo(b.z); fb.y = bfhi(a.z) + bfhi(b.z);
    fb.z = bflo(a.w) + bflo(b.w); fb.w = bfhi(a.w) + bfhi(b.w);
    o[2 * c] = fa;
    o[2 * c + 1] = fb;
  }
}

// ================================= launch ==================================
extern "C" void kernel_launch(void* const* d_in, const int* in_sizes, int n_in,
                              void* d_out, int out_size, void* d_ws, size_t ws_size,
                              hipStream_t stream) {
  const float* x  = (const float*)d_in[0];
  const float* Wg = (const float*)d_in[1];
  const float* Wu = (const float*)d_in[2];
  const float* Wd = (const float*)d_in[3];
  const int*   sel = (const int*)d_in[4];
  const float* rw  = (const float*)d_in[5];
  float* out = (float*)d_out;

  char* base = (char*)d_ws;
  size_t off = 0;
  auto take = [&](size_t bytes) { char* p = base + off; off += bytes; return p; };
  unsigned short* xb     = (unsigned short*)take((size_t)T_TOK * H_DIM * 2);
  unsigned short* WguT   = (unsigned short*)take((size_t)E_NUM * 2048 * H_DIM * 2);
  unsigned short* WdT    = (unsigned short*)take((size_t)E_NUM * H_DIM * I_DIM * 2);
  unsigned short* a_pair = (unsigned short*)take((size_t)CAP * I_DIM * 2);
  unsigned short* d_pair = (unsigned short*)take((size_t)CAP * H_DIM * 2);
  int*   pair_token  = (int*)take(CAP * 4);
  float* pair_weight = (float*)take(CAP * 4);
  int*   inv         = (int*)take(NPAIR * 4);
  int*   tile_expert = (int*)take(512);
  int*   tile_pos    = (int*)take(512);
  (void)off;

  hipFuncSetAttribute((const void*)&moe_gemm<0>,
                      hipFuncAttributeMaxDynamicSharedMemorySize, 131072);
  hipFuncSetAttribute((const void*)&moe_gemm<1>,
                      hipFuncAttributeMaxDynamicSharedMemorySize, 131072);

  prep_all<<<PREP_BLKS, 512, 0, stream>>>(
      (const float4*)x, (ushort4*)xb, Wg, Wu, Wd, WguT, WdT, sel, rw,
      pair_token, pair_weight, inv, tile_expert, tile_pos);

  moe_gemm<0><<<NTB, 512, 131072, stream>>>(
      xb, WguT, pair_token, pair_weight, tile_expert, tile_pos,
      (unsigned int*)a_pair, nullptr);

  moe_gemm<1><<<NTB, 512, 131072, stream>>>(
      a_pair, WdT, pair_token, pair_weight, tile_expert, tile_pos,
      nullptr, d_pair);

  combine<<<T_TOK / 2, 256, 0, stream>>>(d_pair, inv, out);
}